// Round 1
// baseline (173.589 us; speedup 1.0000x reference)
//
#include <hip/hip_runtime.h>
#include <cstdint>
#include <cstddef>

#define BATCH 64
#define PRI   8732
#define NCLS  81
#define NEGPOS 3
#define NTOT  (BATCH * PRI)

__device__ __forceinline__ unsigned keymap(float f) {
    unsigned u = __float_as_uint(f);
    return (u & 0x80000000u) ? ~u : (u | 0x80000000u);
}

// Kernel 1: one wave per prior. logsumexp over 81 classes -> bg_loss, ce.
__global__ __launch_bounds__(256) void k_lse(const float* __restrict__ conf,
                                             const int* __restrict__ labels,
                                             float* __restrict__ bg,
                                             float* __restrict__ ce) {
    const int wave = blockIdx.x * (blockDim.x >> 6) + (threadIdx.x >> 6);
    const int lane = threadIdx.x & 63;
    if (wave >= NTOT) return;

    const float* base = conf + (size_t)wave * NCLS;
    float v0 = base[lane];                                   // classes 0..63
    float v1 = (lane < NCLS - 64) ? base[64 + lane] : -INFINITY; // 64..80

    float m = fmaxf(v0, v1);
#pragma unroll
    for (int o = 32; o > 0; o >>= 1) m = fmaxf(m, __shfl_xor(m, o, 64));

    float s = __expf(v0 - m) + ((lane < NCLS - 64) ? __expf(v1 - m) : 0.0f);
#pragma unroll
    for (int o = 32; o > 0; o >>= 1) s += __shfl_xor(s, o, 64);

    float lse = m + __logf(s);
    int lab = labels[wave];   // wave-uniform
    float c0 = __shfl(v0, 0, 64);
    float cl = (lab < 64) ? __shfl(v0, lab, 64) : __shfl(v1, lab - 64, 64);

    if (lane == 0) {
        bg[wave] = lse - c0;
        ce[wave] = lse - cl;
    }
}

// Kernel 2: one block per batch row. num_pos, radix-select k-th largest bg
// among negatives, stable (index-ordered) tie resolution, sum kept ce,
// smooth-L1 over positive loc entries. Writes per-row partials (no atomics).
__global__ __launch_bounds__(1024) void k_row(const int* __restrict__ labels,
                                              const float* __restrict__ bg,
                                              const float* __restrict__ ce,
                                              const float* __restrict__ ploc,
                                              const float* __restrict__ gloc,
                                              float* __restrict__ rowacc) {
    const int row  = blockIdx.x;
    const int tid  = threadIdx.x;
    const int bs   = blockDim.x;      // 1024
    const int wid  = tid >> 6;
    const int lane = tid & 63;
    const int NW   = 1024 / 64;       // 16

    __shared__ unsigned hist[256];
    __shared__ unsigned ured[16];
    __shared__ float red[16], red2[16];
    __shared__ unsigned sh_prefix, sh_r;
    __shared__ int sh_flag;
    __shared__ unsigned warp_tot[16];
    __shared__ unsigned run_eq_s;

    const int*   lab_row = labels + (size_t)row * PRI;
    const float* bg_row  = bg     + (size_t)row * PRI;
    const float* ce_row  = ce     + (size_t)row * PRI;

    // ---- pass 0: count positives
    int np = 0;
    for (int j = tid; j < PRI; j += bs) np += (lab_row[j] > 0) ? 1 : 0;
#pragma unroll
    for (int o = 32; o > 0; o >>= 1) np += __shfl_xor(np, o, 64);
    if (lane == 0) ured[wid] = (unsigned)np;
    __syncthreads();
    unsigned num_pos = 0;
    for (int w = 0; w < NW; ++w) num_pos += ured[w];
    const int k = (int)num_pos * NEGPOS;

    // ---- radix select: K* = k-th largest key among negatives
    unsigned Kstar = 0;
    int r_eq = 0;          // how many key==K* elements (by index order) to keep
    bool take_all = false;
    if (k > 0) {
        unsigned prefix = 0;
        int r = k, flag = 0;
        for (int level = 3; level >= 0 && !flag; --level) {
            const int shift = level * 8;
            for (int i2 = tid; i2 < 256; i2 += bs) hist[i2] = 0;
            __syncthreads();
            for (int j = tid; j < PRI; j += bs) {
                if (lab_row[j] > 0) continue;
                unsigned key = keymap(bg_row[j]);
                if (level < 3 && (key >> (shift + 8)) != (prefix >> (shift + 8))) continue;
                atomicAdd(&hist[(key >> shift) & 255u], 1u);
            }
            __syncthreads();
            if (tid == 0) {
                unsigned cum = 0; int sel = -1;
                for (int bin = 255; bin >= 0; --bin) {
                    cum += hist[bin];
                    if ((int)cum >= r) {
                        r -= (int)(cum - hist[bin]);
                        prefix |= ((unsigned)bin) << shift;
                        sel = bin;
                        break;
                    }
                }
                if (sel < 0) flag = 1;   // k exceeds negative count: take all
                sh_prefix = prefix; sh_r = (unsigned)r; sh_flag = flag;
            }
            __syncthreads();
            prefix = sh_prefix; r = (int)sh_r; flag = sh_flag;
        }
        Kstar = prefix; r_eq = r; take_all = (sh_flag != 0);
    }

    // ---- selection + objectness sum (stable tie-break by index)
    float obj = 0.0f;
    if (tid == 0) run_eq_s = 0;
    __syncthreads();
    for (int basej = 0; basej < PRI; basej += bs) {
        const int j = basej + tid;
        const bool valid = (j < PRI);
        const int lab = valid ? lab_row[j] : 0;
        const bool pos = valid && (lab > 0);
        const bool isneg = valid && !pos;
        bool keep = pos;
        bool eq = false;
        if (isneg && k > 0) {
            if (take_all) keep = true;
            else {
                unsigned key = keymap(bg_row[j]);
                if (key > Kstar) keep = true;
                else if (key == Kstar) eq = true;
            }
        }
        unsigned long long mb = __ballot(eq);
        unsigned pre = (unsigned)__popcll(mb & ((1ULL << lane) - 1ULL));
        if (lane == 0) warp_tot[wid] = (unsigned)__popcll(mb);
        __syncthreads();
        unsigned woff = 0;
        for (int w = 0; w < wid; ++w) woff += warp_tot[w];
        unsigned myidx = run_eq_s + woff + pre;
        unsigned tot = 0;
        if (tid == 0) for (int w = 0; w < NW; ++w) tot += warp_tot[w];
        __syncthreads();
        if (tid == 0) run_eq_s += tot;
        if (eq && myidx < (unsigned)r_eq) keep = true;
        if (keep) obj += ce_row[j];
    }

    // ---- smooth L1 over positive priors
    float sl1 = 0.0f;
    const float* pl_row = ploc + (size_t)row * PRI * 4;
    const float* gl_row = gloc + (size_t)row * PRI * 4;
    for (int j = tid; j < PRI * 4; j += bs) {
        if (lab_row[j >> 2] > 0) {
            float d = pl_row[j] - gl_row[j];
            float a = fabsf(d);
            sl1 += (a < 1.0f) ? 0.5f * d * d : (a - 0.5f);
        }
    }

    // ---- block reduce, write per-row partials
#pragma unroll
    for (int o = 32; o > 0; o >>= 1) {
        obj += __shfl_xor(obj, o, 64);
        sl1 += __shfl_xor(sl1, o, 64);
    }
    __syncthreads();
    if (lane == 0) { red[wid] = obj; red2[wid] = sl1; }
    __syncthreads();
    if (tid == 0) {
        float to = 0.0f, ts = 0.0f;
        for (int w = 0; w < NW; ++w) { to += red[w]; ts += red2[w]; }
        rowacc[row]              = to;
        rowacc[BATCH + row]      = ts;
        rowacc[2 * BATCH + row]  = (float)num_pos;
    }
}

// Kernel 3: reduce 64 per-row partials -> 2 scalars
__global__ __launch_bounds__(64) void k_final(const float* __restrict__ rowacc,
                                              float* __restrict__ out) {
    int lane = threadIdx.x;
    float o = rowacc[lane];
    float s = rowacc[BATCH + lane];
    float n = rowacc[2 * BATCH + lane];
#pragma unroll
    for (int off = 32; off > 0; off >>= 1) {
        o += __shfl_xor(o, off, 64);
        s += __shfl_xor(s, off, 64);
        n += __shfl_xor(n, off, 64);
    }
    if (lane == 0) {
        float npos = fmaxf(n, 1.0f);
        out[0] = o / npos;
        out[1] = s / npos;
    }
}

extern "C" void kernel_launch(void* const* d_in, const int* in_sizes, int n_in,
                              void* d_out, int out_size, void* d_ws, size_t ws_size,
                              hipStream_t stream) {
    const float* pred_loc  = (const float*)d_in[0];
    const float* pred_conf = (const float*)d_in[1];
    const float* gt_loc    = (const float*)d_in[2];
    const int*   gt_labels = (const int*)d_in[3];
    float* out = (float*)d_out;

    float* bg     = (float*)d_ws;            // NTOT floats
    float* ce     = bg + NTOT;               // NTOT floats
    float* rowacc = ce + NTOT;               // 3*BATCH floats

    const int waves_per_block = 4;           // 256 threads
    const int nblk = (NTOT + waves_per_block - 1) / waves_per_block;
    k_lse<<<nblk, 256, 0, stream>>>(pred_conf, gt_labels, bg, ce);
    k_row<<<BATCH, 1024, 0, stream>>>(gt_labels, bg, ce, pred_loc, gt_loc, rowacc);
    k_final<<<1, 64, 0, stream>>>(rowacc, out);
}

// Round 2
// 81.126 us; speedup vs baseline: 2.1398x; 2.1398x over previous
//
#include <hip/hip_runtime.h>
#include <cstdint>
#include <cstddef>

#define BATCH 64
#define PRI   8732
#define NCLS  81
#define NEGPOS 3
#define NTOT  (BATCH * PRI)
#define NBLK_LSE ((NTOT + 255) / 256)   // 2183 exactly

__device__ __forceinline__ unsigned keymap(float f) {
    unsigned u = __float_as_uint(f);
    return (u & 0x80000000u) ? ~u : (u | 0x80000000u);
}

// ---------------------------------------------------------------------------
// Kernel 1: one THREAD per prior. Online softmax over 81 classes with aligned
// float4 streaming; also computes smooth-L1 for positive priors (fused).
// ---------------------------------------------------------------------------
__global__ __launch_bounds__(256) void k_lse(const float* __restrict__ conf,
                                             const int* __restrict__ labels,
                                             const float* __restrict__ ploc,
                                             const float* __restrict__ gloc,
                                             float* __restrict__ bg,
                                             float* __restrict__ ce,
                                             float* __restrict__ slpart) {
    const int p = blockIdx.x * 256 + threadIdx.x;       // prior index, < NTOT
    const size_t g0 = (size_t)p * NCLS;                  // first float index
    const int o = (int)(g0 & 3);                         // 0..3 head offset
    const float4* q4 = reinterpret_cast<const float4*>(conf + (g0 - o));

    float m = -INFINITY, s = 0.0f;
    float c0 = 0.0f;

    // chunk 0 (head): element i valid iff i >= o
    {
        float4 v = q4[0];
        float x0 = (o == 0) ? v.x : -INFINITY;
        float x1 = (o <= 1) ? v.y : -INFINITY;
        float x2 = (o <= 2) ? v.z : -INFINITY;
        float x3 = v.w;                                   // i=3 always valid
        c0 = (o == 0) ? v.x : (o == 1) ? v.y : (o == 2) ? v.z : v.w;
        float m4 = fmaxf(fmaxf(x0, x1), fmaxf(x2, x3));
        float mn = fmaxf(m, m4);                          // finite (x3 valid)
        s = s * __expf(m - mn)
          + __expf(x0 - mn) + __expf(x1 - mn) + __expf(x2 - mn) + __expf(x3 - mn);
        m = mn;
    }
    // chunks 1..19: fully valid for any o in 0..3
#pragma unroll
    for (int j = 1; j < 20; ++j) {
        float4 v = q4[j];
        float m4 = fmaxf(fmaxf(v.x, v.y), fmaxf(v.z, v.w));
        float mn = fmaxf(m, m4);
        s = s * __expf(m - mn)
          + __expf(v.x - mn) + __expf(v.y - mn) + __expf(v.z - mn) + __expf(v.w - mn);
        m = mn;
    }
    // chunk 20 (tail): element i valid iff i <= o
    {
        float4 v = q4[20];
        float x0 = v.x;
        float x1 = (o >= 1) ? v.y : -INFINITY;
        float x2 = (o >= 2) ? v.z : -INFINITY;
        float x3 = (o >= 3) ? v.w : -INFINITY;
        float m4 = fmaxf(fmaxf(x0, x1), fmaxf(x2, x3));
        float mn = fmaxf(m, m4);
        s = s * __expf(m - mn)
          + __expf(x0 - mn) + __expf(x1 - mn) + __expf(x2 - mn) + __expf(x3 - mn);
        m = mn;
    }

    const float lse = m + __logf(s);
    const int lab = labels[p];
    const float cl = conf[g0 + (size_t)lab];              // L1-hot (just streamed)
    bg[p] = lse - c0;
    ce[p] = lse - cl;

    // fused smooth-L1 (positive priors only, ~2%)
    float sl = 0.0f;
    if (lab > 0) {
        const float4 pl = *reinterpret_cast<const float4*>(ploc + (size_t)p * 4);
        const float4 gl = *reinterpret_cast<const float4*>(gloc + (size_t)p * 4);
        float d, a;
        d = pl.x - gl.x; a = fabsf(d); sl += (a < 1.0f) ? 0.5f * d * d : a - 0.5f;
        d = pl.y - gl.y; a = fabsf(d); sl += (a < 1.0f) ? 0.5f * d * d : a - 0.5f;
        d = pl.z - gl.z; a = fabsf(d); sl += (a < 1.0f) ? 0.5f * d * d : a - 0.5f;
        d = pl.w - gl.w; a = fabsf(d); sl += (a < 1.0f) ? 0.5f * d * d : a - 0.5f;
    }
#pragma unroll
    for (int off = 32; off > 0; off >>= 1) sl += __shfl_xor(sl, off, 64);
    __shared__ float slred[4];
    const int wid = threadIdx.x >> 6, lane = threadIdx.x & 63;
    if (lane == 0) slred[wid] = sl;
    __syncthreads();
    if (threadIdx.x == 0)
        slpart[blockIdx.x] = slred[0] + slred[1] + slred[2] + slred[3];
}

// ---------------------------------------------------------------------------
// Kernel 2: one block per batch row. Stage keymapped bg keys in LDS, count
// positives (+ their ce sum), radix-select exact k-th largest negative key
// (wave-private histograms + wave-parallel suffix scan), then sum kept
// negative losses reconstructed from keys (ce == bg for negatives; ties all
// share one bitwise value -> add r_eq * value, no stable ranking needed).
// ---------------------------------------------------------------------------
__global__ __launch_bounds__(1024) void k_row(const int* __restrict__ labels,
                                              const float* __restrict__ bg,
                                              const float* __restrict__ ce,
                                              float* __restrict__ rowacc) {
    const int row  = blockIdx.x;
    const int tid  = threadIdx.x;
    const int wid  = tid >> 6;
    const int lane = tid & 63;

    __shared__ unsigned keys[PRI];          // 34928 B
    __shared__ unsigned hist[16][257];      // wave-private, padded: 16448 B
    __shared__ unsigned ured[16];
    __shared__ float    fred[16];
    __shared__ unsigned sh_prefix, sh_r;
    __shared__ int      sh_flag;

    const int*   lab_row = labels + (size_t)row * PRI;
    const float* bg_row  = bg     + (size_t)row * PRI;
    const float* ce_row  = ce     + (size_t)row * PRI;

    // ---- stage keys + count positives + accumulate positive ce
    unsigned npl = 0;
    float obj = 0.0f;
    for (int j = tid; j < PRI; j += 1024) {
        const int lab = lab_row[j];
        unsigned key;
        if (lab > 0) {                       // positive: excluded from ranking
            key = 0u;                        // neg keys are >= 0x80000000 (bg>=0)
            npl++;
            obj += ce_row[j];
        } else {
            key = keymap(bg_row[j]);
        }
        keys[j] = key;
    }
#pragma unroll
    for (int off = 32; off > 0; off >>= 1) npl += __shfl_xor(npl, off, 64);
    if (lane == 0) ured[wid] = npl;
    __syncthreads();
    unsigned num_pos = 0;
#pragma unroll
    for (int w = 0; w < 16; ++w) num_pos += ured[w];
    const int k = (int)num_pos * NEGPOS;

    // ---- radix select
    unsigned Kstar = 0xFFFFFFFFu;            // k==0 -> select nothing
    int r_eq = 0;
    bool take_all = false;
    if (k > 0) {
        unsigned prefix = 0;
        int r = k, flag = 0;
        unsigned* hist_flat = &hist[0][0];
        for (int level = 3; level >= 0; --level) {
            const int shift = level * 8;
            for (int i = tid; i < 16 * 257; i += 1024) hist_flat[i] = 0;
            __syncthreads();
            for (int j = tid; j < PRI; j += 1024) {
                const unsigned key = keys[j];
                if (key == 0u) continue;
                if (level < 3 && (key >> (shift + 8)) != (prefix >> (shift + 8))) continue;
                atomicAdd(&hist[wid][(key >> shift) & 255u], 1u);
            }
            __syncthreads();
            if (wid == 0) {
                const int b0 = lane * 4;
                unsigned h0 = 0, h1 = 0, h2 = 0, h3 = 0;
#pragma unroll
                for (int w = 0; w < 16; ++w) {
                    h0 += hist[w][b0]; h1 += hist[w][b0 + 1];
                    h2 += hist[w][b0 + 2]; h3 += hist[w][b0 + 3];
                }
                const unsigned loc = h0 + h1 + h2 + h3;
                unsigned ssum = loc;                       // inclusive suffix over lanes
#pragma unroll
                for (int o2 = 1; o2 < 64; o2 <<= 1) {
                    const unsigned t2 = __shfl_down(ssum, o2, 64);
                    if (lane + o2 < 64) ssum += t2;
                }
                const unsigned above = ssum - loc;          // lanes > this one
                const unsigned cum3 = above + h3;
                const unsigned cum2 = cum3 + h2;
                const unsigned cum1 = cum2 + h1;
                const unsigned cum0 = cum1 + h0;
                const unsigned long long msk = __ballot(cum0 >= (unsigned)r);
                if (msk == 0ULL) {
                    if (lane == 0) sh_flag = 1;             // fewer negs than k
                } else {
                    const int L = 63 - __clzll(msk);
                    if (lane == L) {
                        unsigned selbin, cumsel, hsel;
                        if      (cum3 >= (unsigned)r) { selbin = b0 + 3; cumsel = cum3; hsel = h3; }
                        else if (cum2 >= (unsigned)r) { selbin = b0 + 2; cumsel = cum2; hsel = h2; }
                        else if (cum1 >= (unsigned)r) { selbin = b0 + 1; cumsel = cum1; hsel = h1; }
                        else                          { selbin = b0;     cumsel = cum0; hsel = h0; }
                        sh_prefix = prefix | (selbin << shift);
                        sh_r = (unsigned)r - (cumsel - hsel);
                        sh_flag = 0;
                    }
                }
            }
            __syncthreads();
            flag = sh_flag;
            if (flag) break;
            prefix = sh_prefix;
            r = (int)sh_r;
        }
        take_all = (flag != 0);
        if (!take_all) { Kstar = prefix; r_eq = r; }
    }

    // ---- sum selected negative losses from keys (ce == bg for negatives)
    if (k > 0) {
        for (int j = tid; j < PRI; j += 1024) {
            const unsigned key = keys[j];
            if (key != 0u && (take_all || key > Kstar))
                obj += __uint_as_float(key ^ 0x80000000u);
        }
        if (tid == 0 && !take_all)
            obj += (float)r_eq * __uint_as_float(Kstar ^ 0x80000000u);
    }

    // ---- block reduce, write per-row partials
#pragma unroll
    for (int off = 32; off > 0; off >>= 1) obj += __shfl_xor(obj, off, 64);
    __syncthreads();
    if (lane == 0) fred[wid] = obj;
    __syncthreads();
    if (tid == 0) {
        float to = 0.0f;
#pragma unroll
        for (int w = 0; w < 16; ++w) to += fred[w];
        rowacc[row]         = to;
        rowacc[BATCH + row] = (float)num_pos;
    }
}

// ---------------------------------------------------------------------------
// Kernel 3: final reduction -> 2 scalars
// ---------------------------------------------------------------------------
__global__ __launch_bounds__(256) void k_final(const float* __restrict__ rowacc,
                                               const float* __restrict__ slpart,
                                               float* __restrict__ out) {
    const int tid = threadIdx.x;
    float sl = 0.0f;
    for (int i = tid; i < NBLK_LSE; i += 256) sl += slpart[i];
    float obj = 0.0f, np = 0.0f;
    if (tid < BATCH) { obj = rowacc[tid]; np = rowacc[BATCH + tid]; }
#pragma unroll
    for (int off = 32; off > 0; off >>= 1) {
        sl  += __shfl_xor(sl, off, 64);
        obj += __shfl_xor(obj, off, 64);
        np  += __shfl_xor(np, off, 64);
    }
    __shared__ float r0[4], r1[4], r2[4];
    const int wid = tid >> 6, lane = tid & 63;
    if (lane == 0) { r0[wid] = sl; r1[wid] = obj; r2[wid] = np; }
    __syncthreads();
    if (tid == 0) {
        const float tsl  = r0[0] + r0[1] + r0[2] + r0[3];
        const float tobj = r1[0] + r1[1] + r1[2] + r1[3];
        const float tnp  = r2[0] + r2[1] + r2[2] + r2[3];
        const float npos = fmaxf(tnp, 1.0f);
        out[0] = tobj / npos;
        out[1] = tsl / npos;
    }
}

extern "C" void kernel_launch(void* const* d_in, const int* in_sizes, int n_in,
                              void* d_out, int out_size, void* d_ws, size_t ws_size,
                              hipStream_t stream) {
    const float* pred_loc  = (const float*)d_in[0];
    const float* pred_conf = (const float*)d_in[1];
    const float* gt_loc    = (const float*)d_in[2];
    const int*   gt_labels = (const int*)d_in[3];
    float* out = (float*)d_out;

    float* bg     = (float*)d_ws;            // NTOT floats
    float* ce     = bg + NTOT;               // NTOT floats
    float* rowacc = ce + NTOT;               // 2*BATCH floats
    float* slpart = rowacc + 2 * BATCH;      // NBLK_LSE floats

    k_lse<<<NBLK_LSE, 256, 0, stream>>>(pred_conf, gt_labels, pred_loc, gt_loc,
                                        bg, ce, slpart);
    k_row<<<BATCH, 1024, 0, stream>>>(gt_labels, bg, ce, rowacc);
    k_final<<<1, 256, 0, stream>>>(rowacc, slpart, out);
}